// Round 1
// baseline (741.841 us; speedup 1.0000x reference)
//
#include <hip/hip_runtime.h>

#define NN 50000
#define NP 50048
#define NE 800000
#define CH 512

typedef __bf16 bf16x8 __attribute__((ext_vector_type(8)));
typedef float f32x4 __attribute__((ext_vector_type(4)));
typedef unsigned short u16x8 __attribute__((ext_vector_type(8)));

static __device__ __forceinline__ unsigned short f2b(float f){
  unsigned u = __builtin_bit_cast(unsigned, f);
  u = (u + 0x7fffu + ((u >> 16) & 1u)) >> 16;   // RNE f32 -> bf16
  return (unsigned short)u;
}
static __device__ __forceinline__ float b2f(unsigned short h){
  unsigned u = ((unsigned)h) << 16;
  return __builtin_bit_cast(float, u);
}

// ---- x (f32) -> bf16, padded rows [NN, NP) zeroed ----
__global__ void k_convert_x(const float* __restrict__ x, unsigned short* __restrict__ xb){
  int idx = blockIdx.x * blockDim.x + threadIdx.x;
  int base = idx * 8;
  if (base >= NP * CH) return;
  int row = base >> 9;
  u16x8 o;
  if (row < NN){
    const float4* p = (const float4*)(x + base);
    float4 a = p[0], b = p[1];
    o[0]=f2b(a.x); o[1]=f2b(a.y); o[2]=f2b(a.z); o[3]=f2b(a.w);
    o[4]=f2b(b.x); o[5]=f2b(b.y); o[6]=f2b(b.z); o[7]=f2b(b.w);
  } else {
    #pragma unroll
    for (int k=0;k<8;k++) o[k]=0;
  }
  *(u16x8*)(xb + base) = o;
}

// ---- W [K,N] f32 -> Wt [N,K] bf16 (so GEMM B operand is k-contiguous) ----
__global__ void k_trans_w(const float* __restrict__ W, unsigned short* __restrict__ Wt){
  int idx = blockIdx.x * blockDim.x + threadIdx.x;
  if (idx >= CH * CH) return;
  int n = idx >> 9, k = idx & (CH - 1);
  Wt[n * CH + k] = f2b(W[k * CH + n]);
}

// ---- in-degree histogram (real edges only) ----
__global__ void k_deg(const int* __restrict__ ei, int* __restrict__ deg){
  int e = blockIdx.x * blockDim.x + threadIdx.x;
  if (e >= NE) return;
  atomicAdd(&deg[ei[NE + e]], 1);
}

__global__ void k_dinv(const int* __restrict__ deg, float* __restrict__ dinv){
  int i = blockIdx.x * blockDim.x + threadIdx.x;
  if (i >= NN) return;
  dinv[i] = rsqrtf((float)deg[i] + 1.0f);   // +1 = self-loop; deg_total >= 1 always
}

// ---- single-block exclusive scan over 50000 degrees -> row_ptr, cursor ----
__global__ void k_scan(const int* __restrict__ deg, int* __restrict__ row_ptr,
                       int* __restrict__ cursor){
  __shared__ int sh[1024];
  const int t = threadIdx.x;
  const int start = t * 49;
  int end = start + 49; if (end > NN) end = NN;
  int s = 0;
  for (int i = start; i < end; i++) s += deg[i];
  sh[t] = s;
  __syncthreads();
  for (int d = 1; d < 1024; d <<= 1){
    int add = (t >= d) ? sh[t - d] : 0;
    __syncthreads();
    sh[t] += add;
    __syncthreads();
  }
  int o = sh[t] - s;   // exclusive prefix
  for (int i = start; i < end; i++){
    row_ptr[i] = o; cursor[i] = o; o += deg[i];
  }
  if (t == 0) row_ptr[NN] = sh[1023];
}

// ---- bucket edges by dst ----
__global__ void k_bucket(const int* __restrict__ ei, int* __restrict__ cursor,
                         int* __restrict__ csr_src){
  int e = blockIdx.x * blockDim.x + threadIdx.x;
  if (e >= NE) return;
  int src = ei[e], dst = ei[NE + e];
  int pos = atomicAdd(&cursor[dst], 1);
  csr_src[pos] = src;
}

// ---- bf16 MFMA GEMM: C[M,512] = A[M,512] @ Bt[512,512]^T, 128x128 tile ----
__launch_bounds__(256)
__global__ void k_gemm(const unsigned short* __restrict__ A,
                       const unsigned short* __restrict__ Bt,
                       unsigned short* __restrict__ C){
  __shared__ __align__(16) unsigned short As[128][40];  // stride 40 shorts = 80B: 16B-aligned frags, 2-way bank alias (free)
  __shared__ __align__(16) unsigned short Bs[128][40];
  const int t = threadIdx.x;
  const int wave = t >> 6, lane = t & 63;
  const int quad = lane >> 4, l15 = lane & 15;
  const int mw = (wave >> 1) * 64, nw = (wave & 1) * 64;
  const int rowBase = blockIdx.x * 128;
  const int nBase = blockIdx.y * 128;
  const int sr = t >> 1;
  const int sh = (t & 1) * 16;
  const unsigned short* Ag = A + (size_t)(rowBase + sr) * CH + sh;
  const unsigned short* Bg = Bt + (size_t)(nBase + sr) * CH + sh;

  f32x4 acc[4][4];
  #pragma unroll
  for (int i=0;i<4;i++)
    #pragma unroll
    for (int j=0;j<4;j++) acc[i][j] = 0;

  u16x8 a0 = *(const u16x8*)(Ag);
  u16x8 a1 = *(const u16x8*)(Ag + 8);
  u16x8 b0 = *(const u16x8*)(Bg);
  u16x8 b1 = *(const u16x8*)(Bg + 8);

  for (int kb = 32; kb <= CH; kb += 32){
    *(u16x8*)&As[sr][sh]     = a0;
    *(u16x8*)&As[sr][sh + 8] = a1;
    *(u16x8*)&Bs[sr][sh]     = b0;
    *(u16x8*)&Bs[sr][sh + 8] = b1;
    __syncthreads();
    if (kb < CH){   // prefetch next K-tile while MFMAs run
      a0 = *(const u16x8*)(Ag + kb);
      a1 = *(const u16x8*)(Ag + kb + 8);
      b0 = *(const u16x8*)(Bg + kb);
      b1 = *(const u16x8*)(Bg + kb + 8);
    }
    bf16x8 af[4], bfr[4];
    #pragma unroll
    for (int i=0;i<4;i++)
      af[i] = __builtin_bit_cast(bf16x8, *(const u16x8*)&As[mw + i*16 + l15][quad*8]);
    #pragma unroll
    for (int j=0;j<4;j++)
      bfr[j] = __builtin_bit_cast(bf16x8, *(const u16x8*)&Bs[nw + j*16 + l15][quad*8]);
    #pragma unroll
    for (int i=0;i<4;i++)
      #pragma unroll
      for (int j=0;j<4;j++)
        acc[i][j] = __builtin_amdgcn_mfma_f32_16x16x32_bf16(af[i], bfr[j], acc[i][j], 0, 0, 0);
    __syncthreads();
  }

  // C/D layout (m89-verified): col = lane&15, row = quad*4 + reg
  #pragma unroll
  for (int i=0;i<4;i++){
    #pragma unroll
    for (int j=0;j<4;j++){
      int r0 = rowBase + mw + i*16 + quad*4;
      int c  = nBase + nw + j*16 + l15;
      #pragma unroll
      for (int r=0;r<4;r++)
        C[(size_t)(r0 + r) * CH + c] = f2b(acc[i][j][r]);
    }
  }
}

// ---- aggregation: out = relu(dinv_i * sum_{j->i} dinv_j*h_j + dinv_i^2*h_i + b) ----
__launch_bounds__(256)
__global__ void k_agg(const unsigned short* __restrict__ h, const int* __restrict__ row_ptr,
                      const int* __restrict__ csr_src, const float* __restrict__ dinv,
                      const float* __restrict__ bias, unsigned short* __restrict__ out){
  const int node = blockIdx.x * 4 + (threadIdx.x >> 6);
  const int lane = threadIdx.x & 63;
  float acc[8];
  #pragma unroll
  for (int k=0;k<8;k++) acc[k] = 0.f;
  const int rp = row_ptr[node], re = row_ptr[node + 1];
  for (int base = rp; base < re; base += 64){
    int cnt = re - base; if (cnt > 64) cnt = 64;
    int s = 0; float w = 0.f;
    if (base + lane < re){ s = csr_src[base + lane]; w = dinv[s]; }
    for (int j = 0; j < cnt; j++){
      int ss = __shfl(s, j, 64);
      float ww = __shfl(w, j, 64);
      u16x8 hv = *(const u16x8*)(h + (size_t)ss * CH + lane * 8);
      #pragma unroll
      for (int k=0;k<8;k++) acc[k] += ww * b2f(hv[k]);
    }
  }
  const float di = dinv[node];
  u16x8 hs = *(const u16x8*)(h + (size_t)node * CH + lane * 8);
  const float4* bp = (const float4*)(bias + lane * 8);
  float4 bv0 = bp[0], bv1 = bp[1];
  float bb[8] = {bv0.x,bv0.y,bv0.z,bv0.w,bv1.x,bv1.y,bv1.z,bv1.w};
  u16x8 o;
  #pragma unroll
  for (int k=0;k<8;k++){
    float r = di * acc[k] + di * di * b2f(hs[k]) + bb[k];
    r = fmaxf(r, 0.f);
    o[k] = f2b(r);
  }
  *(u16x8*)(out + (size_t)node * CH + lane * 8) = o;
}

// ---- head: logits[i] = h2[i,:] . Wo + bo ----
__launch_bounds__(256)
__global__ void k_head(const unsigned short* __restrict__ h, const float* __restrict__ Wo,
                       const float* __restrict__ bo, float* __restrict__ logits){
  const int node = blockIdx.x * 4 + (threadIdx.x >> 6);
  const int lane = threadIdx.x & 63;
  u16x8 hv = *(const u16x8*)(h + (size_t)node * CH + lane * 8);
  const float4* wp = (const float4*)(Wo + lane * 8);
  float4 w0 = wp[0], w1 = wp[1];
  float v = b2f(hv[0])*w0.x + b2f(hv[1])*w0.y + b2f(hv[2])*w0.z + b2f(hv[3])*w0.w
          + b2f(hv[4])*w1.x + b2f(hv[5])*w1.y + b2f(hv[6])*w1.z + b2f(hv[7])*w1.w;
  #pragma unroll
  for (int off = 32; off > 0; off >>= 1) v += __shfl_down(v, off, 64);
  if (lane == 0) logits[node] = v + bo[0];
}

// ---- softmax: single-block max + sum(exp) ----
__global__ void k_smreduce(const float* __restrict__ logits, float* __restrict__ scr){
  __shared__ float sh[1024];
  const int t = threadIdx.x;
  float m = -3.4e38f;
  for (int i = t; i < NN; i += 1024) m = fmaxf(m, logits[i]);
  sh[t] = m; __syncthreads();
  for (int d = 512; d > 0; d >>= 1){
    if (t < d) sh[t] = fmaxf(sh[t], sh[t + d]);
    __syncthreads();
  }
  m = sh[0];
  __syncthreads();
  float s = 0.f;
  for (int i = t; i < NN; i += 1024) s += expf(logits[i] - m);
  sh[t] = s; __syncthreads();
  for (int d = 512; d > 0; d >>= 1){
    if (t < d) sh[t] += sh[t + d];
    __syncthreads();
  }
  if (t == 0){ scr[0] = m; scr[1] = sh[0]; }
}

__global__ void k_smwrite(const float* __restrict__ logits, const float* __restrict__ scr,
                          float* __restrict__ out){
  int i = blockIdx.x * blockDim.x + threadIdx.x;
  if (i >= NN) return;
  out[i] = expf(logits[i] - scr[0]) / scr[1];
}

extern "C" void kernel_launch(void* const* d_in, const int* in_sizes, int n_in,
                              void* d_out, int out_size, void* d_ws, size_t ws_size,
                              hipStream_t stream){
  const float* x  = (const float*)d_in[0];
  const int*   ei = (const int*)d_in[1];
  const float* W1 = (const float*)d_in[2];
  const float* b1 = (const float*)d_in[3];
  const float* W2 = (const float*)d_in[4];
  const float* b2 = (const float*)d_in[5];
  const float* Wo = (const float*)d_in[6];
  const float* bo = (const float*)d_in[7];
  float* out = (float*)d_out;

  char* ws = (char*)d_ws;
  size_t off = 0;
  auto alloc = [&](size_t bytes) -> void* {
    void* p = ws + off;
    off = (off + bytes + 255) & ~(size_t)255;
    return p;
  };
  unsigned short* B0  = (unsigned short*)alloc((size_t)NP * CH * 2);
  unsigned short* B1  = (unsigned short*)alloc((size_t)NP * CH * 2);
  unsigned short* W1t = (unsigned short*)alloc((size_t)CH * CH * 2);
  unsigned short* W2t = (unsigned short*)alloc((size_t)CH * CH * 2);
  int*   deg     = (int*)alloc((size_t)NN * 4);
  float* dinv    = (float*)alloc((size_t)NN * 4);
  int*   row_ptr = (int*)alloc((size_t)(NN + 1) * 4);
  int*   cursor  = (int*)alloc((size_t)NN * 4);
  int*   csr     = (int*)alloc((size_t)NE * 4);
  float* logits  = (float*)alloc((size_t)NN * 4);
  float* scr     = (float*)alloc(256);

  hipMemsetAsync(deg, 0, (size_t)NN * 4, stream);
  k_convert_x<<<(NP * CH / 8 + 255) / 256, 256, 0, stream>>>(x, B0);
  k_trans_w<<<(CH * CH + 255) / 256, 256, 0, stream>>>(W1, W1t);
  k_trans_w<<<(CH * CH + 255) / 256, 256, 0, stream>>>(W2, W2t);
  k_deg<<<(NE + 255) / 256, 256, 0, stream>>>(ei, deg);
  k_dinv<<<(NN + 255) / 256, 256, 0, stream>>>(deg, dinv);
  k_scan<<<1, 1024, 0, stream>>>(deg, row_ptr, cursor);
  k_bucket<<<(NE + 255) / 256, 256, 0, stream>>>(ei, cursor, csr);

  k_gemm<<<dim3(NP / 128, CH / 128), 256, 0, stream>>>(B0, W1t, B1);
  k_agg<<<(NN + 3) / 4, 256, 0, stream>>>(B1, row_ptr, csr, dinv, b1, B0);
  k_gemm<<<dim3(NP / 128, CH / 128), 256, 0, stream>>>(B0, W2t, B1);
  k_agg<<<(NN + 3) / 4, 256, 0, stream>>>(B1, row_ptr, csr, dinv, b2, B0);

  k_head<<<(NN + 3) / 4, 256, 0, stream>>>(B0, Wo, bo, logits);
  k_smreduce<<<1, 1024, 0, stream>>>(logits, scr);
  k_smwrite<<<(NN + 255) / 256, 256, 0, stream>>>(logits, scr, out);
}

// Round 2
// 725.972 us; speedup vs baseline: 1.0219x; 1.0219x over previous
//
#include <hip/hip_runtime.h>

#define NN 50000
#define NP 50048
#define NE 800000
#define CH 512

typedef __bf16 bf16x8 __attribute__((ext_vector_type(8)));
typedef float f32x4 __attribute__((ext_vector_type(4)));
typedef unsigned short u16x8 __attribute__((ext_vector_type(8)));

static __device__ __forceinline__ unsigned short f2b(float f){
  unsigned u = __builtin_bit_cast(unsigned, f);
  u = (u + 0x7fffu + ((u >> 16) & 1u)) >> 16;   // RNE f32 -> bf16
  return (unsigned short)u;
}
static __device__ __forceinline__ float b2f(unsigned short h){
  unsigned u = ((unsigned)h) << 16;
  return __builtin_bit_cast(float, u);
}
static __device__ __forceinline__ float rdlane_f(float v, int l){
  return __builtin_bit_cast(float, __builtin_amdgcn_readlane(__builtin_bit_cast(int, v), l));
}

// ---- x (f32) -> bf16, padded rows [NN, NP) zeroed ----
__global__ void k_convert_x(const float* __restrict__ x, unsigned short* __restrict__ xb){
  int idx = blockIdx.x * blockDim.x + threadIdx.x;
  int base = idx * 8;
  if (base >= NP * CH) return;
  int row = base >> 9;
  u16x8 o;
  if (row < NN){
    const float4* p = (const float4*)(x + base);
    float4 a = p[0], b = p[1];
    o[0]=f2b(a.x); o[1]=f2b(a.y); o[2]=f2b(a.z); o[3]=f2b(a.w);
    o[4]=f2b(b.x); o[5]=f2b(b.y); o[6]=f2b(b.z); o[7]=f2b(b.w);
  } else {
    #pragma unroll
    for (int k=0;k<8;k++) o[k]=0;
  }
  *(u16x8*)(xb + base) = o;
}

// ---- W [K,N] f32 -> Wt [N,K] bf16 ----
__global__ void k_trans_w(const float* __restrict__ W, unsigned short* __restrict__ Wt){
  int idx = blockIdx.x * blockDim.x + threadIdx.x;
  if (idx >= CH * CH) return;
  int n = idx >> 9, k = idx & (CH - 1);
  Wt[n * CH + k] = f2b(W[k * CH + n]);
}

// ---- in-degree histogram (real edges only) ----
__global__ void k_deg(const int* __restrict__ ei, int* __restrict__ deg){
  int e = blockIdx.x * blockDim.x + threadIdx.x;
  if (e >= NE) return;
  atomicAdd(&deg[ei[NE + e]], 1);
}

// ---- single-block scan over degrees -> row_ptr, cursor; also dinv ----
__global__ void k_scan(const int* __restrict__ deg, int* __restrict__ row_ptr,
                       int* __restrict__ cursor, float* __restrict__ dinv){
  __shared__ int sh[1024];
  const int t = threadIdx.x;
  const int start = t * 49;
  int end = start + 49; if (end > NN) end = NN;
  int s = 0;
  for (int i = start; i < end; i++) s += deg[i];
  sh[t] = s;
  __syncthreads();
  for (int d = 1; d < 1024; d <<= 1){
    int add = (t >= d) ? sh[t - d] : 0;
    __syncthreads();
    sh[t] += add;
    __syncthreads();
  }
  int o = sh[t] - s;   // exclusive prefix
  for (int i = start; i < end; i++){
    int dg = deg[i];
    row_ptr[i] = o; cursor[i] = o; o += dg;
    dinv[i] = rsqrtf((float)dg + 1.0f);   // +1 self-loop
  }
  if (t == 0) row_ptr[NN] = sh[1023];
}

// ---- bucket edges by dst ----
__global__ void k_bucket(const int* __restrict__ ei, int* __restrict__ cursor,
                         int* __restrict__ csr_src){
  int e = blockIdx.x * blockDim.x + threadIdx.x;
  if (e >= NE) return;
  int src = ei[e], dst = ei[NE + e];
  int pos = atomicAdd(&cursor[dst], 1);
  csr_src[pos] = src;
}

// ---- bf16 MFMA GEMM (m97-style): C[M,512] = A @ Bt^T, 128x128 tile ----
// LDS unpadded [128][32] shorts (64B rows) — required by global_load_lds
// (dest = wave-uniform base + lane*16B). Fragment ds_read_b128 pattern is
// conflict-free in the throughput sense (each bank serves exactly 8 words/wave).
__launch_bounds__(256)
__global__ void k_gemm(const unsigned short* __restrict__ A,
                       const unsigned short* __restrict__ Bt,
                       unsigned short* __restrict__ C){
  __shared__ __align__(16) unsigned short As[128 * 32];
  __shared__ __align__(16) unsigned short Bs[128 * 32];
  const int t = threadIdx.x;
  const int wave = t >> 6, lane = t & 63;
  const int quad = lane >> 4, l15 = lane & 15;
  const int mw = (wave >> 1) * 64, nw = (wave & 1) * 64;
  const int rowBase = blockIdx.x * 128;
  const int nBase = blockIdx.y * 128;

  // staging: wave w stages chunks 2w, 2w+1 (16 rows each) of both A and B
  const int c0 = wave * 2;
  const int lr = lane >> 2;            // row within 16-row chunk
  const int lc = (lane & 3) * 8;       // short offset within 32-short row
  const unsigned short* Ag0 = A  + (size_t)(rowBase + c0 * 16 + lr) * CH + lc;
  const unsigned short* Ag1 = Ag0 + 16 * CH;
  const unsigned short* Bg0 = Bt + (size_t)(nBase + c0 * 16 + lr) * CH + lc;
  const unsigned short* Bg1 = Bg0 + 16 * CH;
  unsigned short* Al0 = As + c0 * 512;        // wave-uniform LDS chunk bases
  unsigned short* Al1 = As + c0 * 512 + 512;
  unsigned short* Bl0 = Bs + c0 * 512;
  unsigned short* Bl1 = Bs + c0 * 512 + 512;

  f32x4 acc[4][4];
  #pragma unroll
  for (int i=0;i<4;i++)
    #pragma unroll
    for (int j=0;j<4;j++) acc[i][j] = 0;

  for (int kb = 0; kb < CH; kb += 32){
    __builtin_amdgcn_global_load_lds(
      (const __attribute__((address_space(1))) void*)(Ag0 + kb),
      (__attribute__((address_space(3))) void*)Al0, 16, 0, 0);
    __builtin_amdgcn_global_load_lds(
      (const __attribute__((address_space(1))) void*)(Ag1 + kb),
      (__attribute__((address_space(3))) void*)Al1, 16, 0, 0);
    __builtin_amdgcn_global_load_lds(
      (const __attribute__((address_space(1))) void*)(Bg0 + kb),
      (__attribute__((address_space(3))) void*)Bl0, 16, 0, 0);
    __builtin_amdgcn_global_load_lds(
      (const __attribute__((address_space(1))) void*)(Bg1 + kb),
      (__attribute__((address_space(3))) void*)Bl1, 16, 0, 0);
    __syncthreads();

    bf16x8 af[4], bfr[4];
    #pragma unroll
    for (int i=0;i<4;i++)
      af[i] = __builtin_bit_cast(bf16x8,
              *(const u16x8*)&As[(mw + i*16 + l15) * 32 + quad * 8]);
    #pragma unroll
    for (int j=0;j<4;j++)
      bfr[j] = __builtin_bit_cast(bf16x8,
              *(const u16x8*)&Bs[(nw + j*16 + l15) * 32 + quad * 8]);
    #pragma unroll
    for (int i=0;i<4;i++)
      #pragma unroll
      for (int j=0;j<4;j++)
        acc[i][j] = __builtin_amdgcn_mfma_f32_16x16x32_bf16(af[i], bfr[j], acc[i][j], 0, 0, 0);
    __syncthreads();
  }

  // C/D layout (m89-verified): col = lane&15, row = quad*4 + reg
  #pragma unroll
  for (int i=0;i<4;i++){
    #pragma unroll
    for (int j=0;j<4;j++){
      int r0 = rowBase + mw + i*16 + quad*4;
      int c  = nBase + nw + j*16 + l15;
      #pragma unroll
      for (int r=0;r<4;r++)
        C[(size_t)(r0 + r) * CH + c] = f2b(acc[i][j][r]);
    }
  }
}

// ---- aggregation: relu(dinv_i * sum dinv_j*h_j + dinv_i^2*h_i + b); optional head fuse ----
template<bool HEAD>
__launch_bounds__(256)
__global__ void k_agg(const unsigned short* __restrict__ h, const int* __restrict__ row_ptr,
                      const int* __restrict__ csr_src, const float* __restrict__ dinv,
                      const float* __restrict__ bias, unsigned short* __restrict__ out,
                      const float* __restrict__ Wo, const float* __restrict__ bo,
                      float* __restrict__ logits){
  const int node = blockIdx.x * 4 + (threadIdx.x >> 6);
  const int lane = threadIdx.x & 63;
  float acc[8];
  #pragma unroll
  for (int k=0;k<8;k++) acc[k] = 0.f;
  const int rp = row_ptr[node], re = row_ptr[node + 1];
  for (int base = rp; base < re; base += 64){
    int cnt = re - base; if (cnt > 64) cnt = 64;
    int s = 0; float w = 0.f;
    if (base + lane < re){ s = csr_src[base + lane]; w = dinv[s]; }
    int j = 0;
    for (; j + 8 <= cnt; j += 8){            // 8 outstanding row loads
      int ss[8]; float ww[8]; u16x8 hv[8];
      #pragma unroll
      for (int u=0;u<8;u++){
        ss[u] = __builtin_amdgcn_readlane(s, j + u);
        ww[u] = rdlane_f(w, j + u);
      }
      #pragma unroll
      for (int u=0;u<8;u++)
        hv[u] = *(const u16x8*)(h + (size_t)ss[u] * CH + lane * 8);
      #pragma unroll
      for (int u=0;u<8;u++)
        #pragma unroll
        for (int k=0;k<8;k++) acc[k] += ww[u] * b2f(hv[u][k]);
    }
    for (; j < cnt; j++){
      int ss = __builtin_amdgcn_readlane(s, j);
      float ww = rdlane_f(w, j);
      u16x8 hv = *(const u16x8*)(h + (size_t)ss * CH + lane * 8);
      #pragma unroll
      for (int k=0;k<8;k++) acc[k] += ww * b2f(hv[k]);
    }
  }
  const float di = dinv[node];
  u16x8 hs = *(const u16x8*)(h + (size_t)node * CH + lane * 8);
  const float4* bp = (const float4*)(bias + lane * 8);
  float4 bv0 = bp[0], bv1 = bp[1];
  float bb[8] = {bv0.x,bv0.y,bv0.z,bv0.w,bv1.x,bv1.y,bv1.z,bv1.w};
  if (HEAD){
    const float4* wp = (const float4*)(Wo + lane * 8);
    float4 w0 = wp[0], w1 = wp[1];
    float wv[8] = {w0.x,w0.y,w0.z,w0.w,w1.x,w1.y,w1.z,w1.w};
    float v = 0.f;
    #pragma unroll
    for (int k=0;k<8;k++){
      float r = fmaxf(di * acc[k] + di * di * b2f(hs[k]) + bb[k], 0.f);
      v += r * wv[k];
    }
    #pragma unroll
    for (int off = 32; off > 0; off >>= 1) v += __shfl_down(v, off, 64);
    if (lane == 0) logits[node] = v + bo[0];
  } else {
    u16x8 o;
    #pragma unroll
    for (int k=0;k<8;k++){
      float r = fmaxf(di * acc[k] + di * di * b2f(hs[k]) + bb[k], 0.f);
      o[k] = f2b(r);
    }
    *(u16x8*)(out + (size_t)node * CH + lane * 8) = o;
  }
}

// ---- softmax: single-block max + sum(exp), float4 ----
__global__ void k_smreduce(const float* __restrict__ logits, float* __restrict__ scr){
  __shared__ float sh[1024];
  const int t = threadIdx.x;
  const float4* L4 = (const float4*)logits;  // 50000/4 = 12500 exact
  float m = -3.4e38f;
  for (int i = t; i < 12500; i += 1024){
    float4 v = L4[i];
    m = fmaxf(m, fmaxf(fmaxf(v.x, v.y), fmaxf(v.z, v.w)));
  }
  sh[t] = m; __syncthreads();
  for (int d = 512; d > 0; d >>= 1){
    if (t < d) sh[t] = fmaxf(sh[t], sh[t + d]);
    __syncthreads();
  }
  m = sh[0];
  __syncthreads();
  float s = 0.f;
  for (int i = t; i < 12500; i += 1024){
    float4 v = L4[i];
    s += expf(v.x - m) + expf(v.y - m) + expf(v.z - m) + expf(v.w - m);
  }
  sh[t] = s; __syncthreads();
  for (int d = 512; d > 0; d >>= 1){
    if (t < d) sh[t] += sh[t + d];
    __syncthreads();
  }
  if (t == 0){ scr[0] = m; scr[1] = sh[0]; }
}

__global__ void k_smwrite(const float* __restrict__ logits, const float* __restrict__ scr,
                          float* __restrict__ out){
  int i = blockIdx.x * blockDim.x + threadIdx.x;
  if (i >= NN) return;
  out[i] = expf(logits[i] - scr[0]) / scr[1];
}

extern "C" void kernel_launch(void* const* d_in, const int* in_sizes, int n_in,
                              void* d_out, int out_size, void* d_ws, size_t ws_size,
                              hipStream_t stream){
  const float* x  = (const float*)d_in[0];
  const int*   ei = (const int*)d_in[1];
  const float* W1 = (const float*)d_in[2];
  const float* b1 = (const float*)d_in[3];
  const float* W2 = (const float*)d_in[4];
  const float* b2 = (const float*)d_in[5];
  const float* Wo = (const float*)d_in[6];
  const float* bo = (const float*)d_in[7];
  float* out = (float*)d_out;

  char* ws = (char*)d_ws;
  size_t off = 0;
  auto alloc = [&](size_t bytes) -> void* {
    void* p = ws + off;
    off = (off + bytes + 255) & ~(size_t)255;
    return p;
  };
  unsigned short* B0  = (unsigned short*)alloc((size_t)NP * CH * 2);
  unsigned short* B1  = (unsigned short*)alloc((size_t)NP * CH * 2);
  unsigned short* W1t = (unsigned short*)alloc((size_t)CH * CH * 2);
  unsigned short* W2t = (unsigned short*)alloc((size_t)CH * CH * 2);
  int*   deg     = (int*)alloc((size_t)NN * 4);
  float* dinv    = (float*)alloc((size_t)NN * 4);
  int*   row_ptr = (int*)alloc((size_t)(NN + 1) * 4);
  int*   cursor  = (int*)alloc((size_t)NN * 4);
  int*   csr     = (int*)alloc((size_t)NE * 4);
  float* logits  = (float*)alloc((size_t)NN * 4);
  float* scr     = (float*)alloc(256);

  hipMemsetAsync(deg, 0, (size_t)NN * 4, stream);
  k_convert_x<<<(NP * CH / 8 + 255) / 256, 256, 0, stream>>>(x, B0);
  k_trans_w<<<(CH * CH + 255) / 256, 256, 0, stream>>>(W1, W1t);
  k_trans_w<<<(CH * CH + 255) / 256, 256, 0, stream>>>(W2, W2t);
  k_deg<<<(NE + 255) / 256, 256, 0, stream>>>(ei, deg);
  k_scan<<<1, 1024, 0, stream>>>(deg, row_ptr, cursor, dinv);
  k_bucket<<<(NE + 255) / 256, 256, 0, stream>>>(ei, cursor, csr);

  k_gemm<<<dim3(NP / 128, CH / 128), 256, 0, stream>>>(B0, W1t, B1);
  k_agg<false><<<NN / 4, 256, 0, stream>>>(B1, row_ptr, csr, dinv, b1, B0,
                                           Wo, bo, logits);
  k_gemm<<<dim3(NP / 128, CH / 128), 256, 0, stream>>>(B0, W2t, B1);
  k_agg<true><<<NN / 4, 256, 0, stream>>>(B1, row_ptr, csr, dinv, b2, B0,
                                          Wo, bo, logits);

  k_smreduce<<<1, 1024, 0, stream>>>(logits, scr);
  k_smwrite<<<(NN + 255) / 256, 256, 0, stream>>>(logits, scr, out);
}

// Round 3
// 599.840 us; speedup vs baseline: 1.2367x; 1.2103x over previous
//
#include <hip/hip_runtime.h>

#define NN 50000
#define NP 50048
#define NE 800000
#define CH 512
#define NB 196   // ceil(50000/256) scan blocks

typedef __bf16 bf16x8 __attribute__((ext_vector_type(8)));
typedef float f32x4 __attribute__((ext_vector_type(4)));
typedef unsigned short u16x8 __attribute__((ext_vector_type(8)));

static __device__ __forceinline__ unsigned short f2b(float f){
  unsigned u = __builtin_bit_cast(unsigned, f);
  u = (u + 0x7fffu + ((u >> 16) & 1u)) >> 16;   // RNE f32 -> bf16
  return (unsigned short)u;
}
static __device__ __forceinline__ float b2f(unsigned short h){
  unsigned u = ((unsigned)h) << 16;
  return __builtin_bit_cast(float, u);
}
static __device__ __forceinline__ float rdlane_f(float v, int l){
  return __builtin_bit_cast(float, __builtin_amdgcn_readlane(__builtin_bit_cast(int, v), l));
}

// ---- x (f32) -> bf16, padded rows [NN, NP) zeroed ----
__global__ void k_convert_x(const float* __restrict__ x, unsigned short* __restrict__ xb){
  int idx = blockIdx.x * blockDim.x + threadIdx.x;
  int base = idx * 8;
  if (base >= NP * CH) return;
  int row = base >> 9;
  u16x8 o;
  if (row < NN){
    const float4* p = (const float4*)(x + base);
    float4 a = p[0], b = p[1];
    o[0]=f2b(a.x); o[1]=f2b(a.y); o[2]=f2b(a.z); o[3]=f2b(a.w);
    o[4]=f2b(b.x); o[5]=f2b(b.y); o[6]=f2b(b.z); o[7]=f2b(b.w);
  } else {
    #pragma unroll
    for (int k=0;k<8;k++) o[k]=0;
  }
  *(u16x8*)(xb + base) = o;
}

// ---- W [K,N] f32 -> Wt [N,K] bf16 ----
__global__ void k_trans_w(const float* __restrict__ W, unsigned short* __restrict__ Wt){
  int idx = blockIdx.x * blockDim.x + threadIdx.x;
  if (idx >= CH * CH) return;
  int n = idx >> 9, k = idx & (CH - 1);
  Wt[n * CH + k] = f2b(W[k * CH + n]);
}

// ---- in-degree histogram (real edges only) ----
__global__ void k_deg(const int* __restrict__ ei, int* __restrict__ deg){
  int e = blockIdx.x * blockDim.x + threadIdx.x;
  if (e >= NE) return;
  atomicAdd(&deg[ei[NE + e]], 1);
}

// ---- hierarchical scan: 196-block sums -> scan sums -> scatter ----
__global__ void k_blocksum(const int* __restrict__ deg, int* __restrict__ bsum){
  __shared__ int sh[4];
  const int t = threadIdx.x;
  int i = blockIdx.x * 256 + t;
  int v = (i < NN) ? deg[i] : 0;
  #pragma unroll
  for (int off = 32; off > 0; off >>= 1) v += __shfl_down(v, off, 64);
  if ((t & 63) == 0) sh[t >> 6] = v;
  __syncthreads();
  if (t == 0) bsum[blockIdx.x] = sh[0] + sh[1] + sh[2] + sh[3];
}

__global__ void k_scanoff(const int* __restrict__ bsum, int* __restrict__ boff,
                          int* __restrict__ row_ptr){
  __shared__ int sh[256];
  const int t = threadIdx.x;
  int v = (t < NB) ? bsum[t] : 0;
  sh[t] = v; __syncthreads();
  for (int d = 1; d < 256; d <<= 1){
    int add = (t >= d) ? sh[t - d] : 0;
    __syncthreads();
    sh[t] += add;
    __syncthreads();
  }
  if (t < NB) boff[t] = sh[t] - v;      // exclusive block offset
  if (t == 255) row_ptr[NN] = sh[255];  // grand total
}

__global__ void k_scatter(const int* __restrict__ deg, const int* __restrict__ boff,
                          int* __restrict__ row_ptr, int* __restrict__ cursor,
                          float* __restrict__ dinv){
  __shared__ int sh[256];
  const int t = threadIdx.x;
  int i = blockIdx.x * 256 + t;
  int d = (i < NN) ? deg[i] : 0;
  sh[t] = d; __syncthreads();
  for (int dd = 1; dd < 256; dd <<= 1){
    int add = (t >= dd) ? sh[t - dd] : 0;
    __syncthreads();
    sh[t] += add;
    __syncthreads();
  }
  if (i < NN){
    int ex = sh[t] - d + boff[blockIdx.x];
    row_ptr[i] = ex; cursor[i] = ex;
    dinv[i] = rsqrtf((float)d + 1.0f);   // +1 self-loop
  }
}

// ---- bucket edges by dst ----
__global__ void k_bucket(const int* __restrict__ ei, int* __restrict__ cursor,
                         int* __restrict__ csr_src){
  int e = blockIdx.x * blockDim.x + threadIdx.x;
  if (e >= NE) return;
  int src = ei[e], dst = ei[NE + e];
  int pos = atomicAdd(&cursor[dst], 1);
  csr_src[pos] = src;
}

// ---- bf16 MFMA GEMM (m97-style): C[M,512] = A @ Bt^T, 128x128 tile ----
__launch_bounds__(256)
__global__ void k_gemm(const unsigned short* __restrict__ A,
                       const unsigned short* __restrict__ Bt,
                       unsigned short* __restrict__ C){
  __shared__ __align__(16) unsigned short As[128 * 32];
  __shared__ __align__(16) unsigned short Bs[128 * 32];
  const int t = threadIdx.x;
  const int wave = t >> 6, lane = t & 63;
  const int quad = lane >> 4, l15 = lane & 15;
  const int mw = (wave >> 1) * 64, nw = (wave & 1) * 64;
  const int rowBase = blockIdx.x * 128;
  const int nBase = blockIdx.y * 128;

  const int c0 = wave * 2;
  const int lr = lane >> 2;
  const int lc = (lane & 3) * 8;
  const unsigned short* Ag0 = A  + (size_t)(rowBase + c0 * 16 + lr) * CH + lc;
  const unsigned short* Ag1 = Ag0 + 16 * CH;
  const unsigned short* Bg0 = Bt + (size_t)(nBase + c0 * 16 + lr) * CH + lc;
  const unsigned short* Bg1 = Bg0 + 16 * CH;
  unsigned short* Al0 = As + c0 * 512;
  unsigned short* Al1 = As + c0 * 512 + 512;
  unsigned short* Bl0 = Bs + c0 * 512;
  unsigned short* Bl1 = Bs + c0 * 512 + 512;

  f32x4 acc[4][4];
  #pragma unroll
  for (int i=0;i<4;i++)
    #pragma unroll
    for (int j=0;j<4;j++) acc[i][j] = 0;

  for (int kb = 0; kb < CH; kb += 32){
    __builtin_amdgcn_global_load_lds(
      (const __attribute__((address_space(1))) void*)(Ag0 + kb),
      (__attribute__((address_space(3))) void*)Al0, 16, 0, 0);
    __builtin_amdgcn_global_load_lds(
      (const __attribute__((address_space(1))) void*)(Ag1 + kb),
      (__attribute__((address_space(3))) void*)Al1, 16, 0, 0);
    __builtin_amdgcn_global_load_lds(
      (const __attribute__((address_space(1))) void*)(Bg0 + kb),
      (__attribute__((address_space(3))) void*)Bl0, 16, 0, 0);
    __builtin_amdgcn_global_load_lds(
      (const __attribute__((address_space(1))) void*)(Bg1 + kb),
      (__attribute__((address_space(3))) void*)Bl1, 16, 0, 0);
    __syncthreads();

    bf16x8 af[4], bfr[4];
    #pragma unroll
    for (int i=0;i<4;i++)
      af[i] = __builtin_bit_cast(bf16x8,
              *(const u16x8*)&As[(mw + i*16 + l15) * 32 + quad * 8]);
    #pragma unroll
    for (int j=0;j<4;j++)
      bfr[j] = __builtin_bit_cast(bf16x8,
              *(const u16x8*)&Bs[(nw + j*16 + l15) * 32 + quad * 8]);
    #pragma unroll
    for (int i=0;i<4;i++)
      #pragma unroll
      for (int j=0;j<4;j++)
        acc[i][j] = __builtin_amdgcn_mfma_f32_16x16x32_bf16(af[i], bfr[j], acc[i][j], 0, 0, 0);
    __syncthreads();
  }

  // C/D layout (m89-verified): col = lane&15, row = quad*4 + reg
  #pragma unroll
  for (int i=0;i<4;i++){
    #pragma unroll
    for (int j=0;j<4;j++){
      int r0 = rowBase + mw + i*16 + quad*4;
      int c  = nBase + nw + j*16 + l15;
      #pragma unroll
      for (int r=0;r<4;r++)
        C[(size_t)(r0 + r) * CH + c] = f2b(acc[i][j][r]);
    }
  }
}

// ---- aggregation: relu(dinv_i * sum dinv_j*h_j + dinv_i^2*h_i + b); optional head fuse ----
template<bool HEAD>
__launch_bounds__(256)
__global__ void k_agg(const unsigned short* __restrict__ h, const int* __restrict__ row_ptr,
                      const int* __restrict__ csr_src, const float* __restrict__ dinv,
                      const float* __restrict__ bias, unsigned short* __restrict__ out,
                      const float* __restrict__ Wo, const float* __restrict__ bo,
                      float* __restrict__ logits){
  const int node = blockIdx.x * 4 + (threadIdx.x >> 6);
  const int lane = threadIdx.x & 63;
  float acc[8];
  #pragma unroll
  for (int k=0;k<8;k++) acc[k] = 0.f;
  const int rp = row_ptr[node], re = row_ptr[node + 1];
  for (int base = rp; base < re; base += 64){
    int cnt = re - base; if (cnt > 64) cnt = 64;
    int s = 0; float w = 0.f;
    if (base + lane < re){ s = csr_src[base + lane]; w = dinv[s]; }
    int j = 0;
    for (; j + 8 <= cnt; j += 8){            // 8 outstanding row loads
      int ss[8]; float ww[8]; u16x8 hv[8];
      #pragma unroll
      for (int u=0;u<8;u++){
        ss[u] = __builtin_amdgcn_readlane(s, j + u);
        ww[u] = rdlane_f(w, j + u);
      }
      #pragma unroll
      for (int u=0;u<8;u++)
        hv[u] = *(const u16x8*)(h + (size_t)ss[u] * CH + lane * 8);
      #pragma unroll
      for (int u=0;u<8;u++)
        #pragma unroll
        for (int k=0;k<8;k++) acc[k] += ww[u] * b2f(hv[u][k]);
    }
    for (; j < cnt; j++){
      int ss = __builtin_amdgcn_readlane(s, j);
      float ww = rdlane_f(w, j);
      u16x8 hv = *(const u16x8*)(h + (size_t)ss * CH + lane * 8);
      #pragma unroll
      for (int k=0;k<8;k++) acc[k] += ww * b2f(hv[k]);
    }
  }
  const float di = dinv[node];
  u16x8 hs = *(const u16x8*)(h + (size_t)node * CH + lane * 8);
  const float4* bp = (const float4*)(bias + lane * 8);
  float4 bv0 = bp[0], bv1 = bp[1];
  float bb[8] = {bv0.x,bv0.y,bv0.z,bv0.w,bv1.x,bv1.y,bv1.z,bv1.w};
  if (HEAD){
    const float4* wp = (const float4*)(Wo + lane * 8);
    float4 w0 = wp[0], w1 = wp[1];
    float wv[8] = {w0.x,w0.y,w0.z,w0.w,w1.x,w1.y,w1.z,w1.w};
    float v = 0.f;
    #pragma unroll
    for (int k=0;k<8;k++){
      float r = fmaxf(di * acc[k] + di * di * b2f(hs[k]) + bb[k], 0.f);
      v += r * wv[k];
    }
    #pragma unroll
    for (int off = 32; off > 0; off >>= 1) v += __shfl_down(v, off, 64);
    if (lane == 0) logits[node] = v + bo[0];
  } else {
    u16x8 o;
    #pragma unroll
    for (int k=0;k<8;k++){
      float r = fmaxf(di * acc[k] + di * di * b2f(hs[k]) + bb[k], 0.f);
      o[k] = f2b(r);
    }
    *(u16x8*)(out + (size_t)node * CH + lane * 8) = o;
  }
}

// ---- softmax: single-block max + sum(exp), float4 ----
__global__ void k_smreduce(const float* __restrict__ logits, float* __restrict__ scr){
  __shared__ float sh[1024];
  const int t = threadIdx.x;
  const float4* L4 = (const float4*)logits;  // 50000/4 = 12500 exact
  float m = -3.4e38f;
  for (int i = t; i < 12500; i += 1024){
    float4 v = L4[i];
    m = fmaxf(m, fmaxf(fmaxf(v.x, v.y), fmaxf(v.z, v.w)));
  }
  sh[t] = m; __syncthreads();
  for (int d = 512; d > 0; d >>= 1){
    if (t < d) sh[t] = fmaxf(sh[t], sh[t + d]);
    __syncthreads();
  }
  m = sh[0];
  __syncthreads();
  float s = 0.f;
  for (int i = t; i < 12500; i += 1024){
    float4 v = L4[i];
    s += expf(v.x - m) + expf(v.y - m) + expf(v.z - m) + expf(v.w - m);
  }
  sh[t] = s; __syncthreads();
  for (int d = 512; d > 0; d >>= 1){
    if (t < d) sh[t] += sh[t + d];
    __syncthreads();
  }
  if (t == 0){ scr[0] = m; scr[1] = sh[0]; }
}

__global__ void k_smwrite(const float* __restrict__ logits, const float* __restrict__ scr,
                          float* __restrict__ out){
  int i = blockIdx.x * blockDim.x + threadIdx.x;
  if (i >= NN) return;
  out[i] = expf(logits[i] - scr[0]) / scr[1];
}

extern "C" void kernel_launch(void* const* d_in, const int* in_sizes, int n_in,
                              void* d_out, int out_size, void* d_ws, size_t ws_size,
                              hipStream_t stream){
  const float* x  = (const float*)d_in[0];
  const int*   ei = (const int*)d_in[1];
  const float* W1 = (const float*)d_in[2];
  const float* b1 = (const float*)d_in[3];
  const float* W2 = (const float*)d_in[4];
  const float* b2 = (const float*)d_in[5];
  const float* Wo = (const float*)d_in[6];
  const float* bo = (const float*)d_in[7];
  float* out = (float*)d_out;

  char* ws = (char*)d_ws;
  size_t off = 0;
  auto alloc = [&](size_t bytes) -> void* {
    void* p = ws + off;
    off = (off + bytes + 255) & ~(size_t)255;
    return p;
  };
  unsigned short* B0  = (unsigned short*)alloc((size_t)NP * CH * 2);
  unsigned short* B1  = (unsigned short*)alloc((size_t)NP * CH * 2);
  unsigned short* W1t = (unsigned short*)alloc((size_t)CH * CH * 2);
  unsigned short* W2t = (unsigned short*)alloc((size_t)CH * CH * 2);
  int*   deg     = (int*)alloc((size_t)NN * 4);
  float* dinv    = (float*)alloc((size_t)NN * 4);
  int*   row_ptr = (int*)alloc((size_t)(NN + 1) * 4);
  int*   cursor  = (int*)alloc((size_t)NN * 4);
  int*   csr     = (int*)alloc((size_t)NE * 4);
  float* logits  = (float*)alloc((size_t)NN * 4);
  int*   bsum    = (int*)alloc((size_t)NB * 4);
  int*   boff    = (int*)alloc((size_t)NB * 4);
  float* scr     = (float*)alloc(256);

  hipMemsetAsync(deg, 0, (size_t)NN * 4, stream);
  k_convert_x<<<(NP * CH / 8 + 255) / 256, 256, 0, stream>>>(x, B0);
  k_trans_w<<<(CH * CH + 255) / 256, 256, 0, stream>>>(W1, W1t);
  k_trans_w<<<(CH * CH + 255) / 256, 256, 0, stream>>>(W2, W2t);
  k_deg<<<(NE + 255) / 256, 256, 0, stream>>>(ei, deg);
  k_blocksum<<<NB, 256, 0, stream>>>(deg, bsum);
  k_scanoff<<<1, 256, 0, stream>>>(bsum, boff, row_ptr);
  k_scatter<<<NB, 256, 0, stream>>>(deg, boff, row_ptr, cursor, dinv);
  k_bucket<<<(NE + 255) / 256, 256, 0, stream>>>(ei, cursor, csr);

  k_gemm<<<dim3(NP / 128, CH / 128), 256, 0, stream>>>(B0, W1t, B1);
  k_agg<false><<<NN / 4, 256, 0, stream>>>(B1, row_ptr, csr, dinv, b1, B0,
                                           Wo, bo, logits);
  k_gemm<<<dim3(NP / 128, CH / 128), 256, 0, stream>>>(B0, W2t, B1);
  k_agg<true><<<NN / 4, 256, 0, stream>>>(B1, row_ptr, csr, dinv, b2, B0,
                                          Wo, bo, logits);

  k_smreduce<<<1, 1024, 0, stream>>>(logits, scr);
  k_smwrite<<<(NN + 255) / 256, 256, 0, stream>>>(logits, scr, out);
}

// Round 4
// 584.838 us; speedup vs baseline: 1.2685x; 1.0257x over previous
//
#include <hip/hip_runtime.h>

#define NN 50000
#define NP 50048
#define NE 800000
#define CH 512
#define NB 196        // ceil(50000/256) scan blocks
#define PB_CONV 12512 // NP*CH/8/256
#define PB_TRANS 2048 // 2 * CH*CH/256
#define PB_DEG 782    // ceil(NE/4/256)
#define SMB 49        // softmax partial blocks (49*1024 >= 50000)

typedef __bf16 bf16x8 __attribute__((ext_vector_type(8)));
typedef float f32x4 __attribute__((ext_vector_type(4)));
typedef unsigned short u16x8 __attribute__((ext_vector_type(8)));

static __device__ __forceinline__ unsigned short f2b(float f){
  unsigned u = __builtin_bit_cast(unsigned, f);
  u = (u + 0x7fffu + ((u >> 16) & 1u)) >> 16;   // RNE f32 -> bf16
  return (unsigned short)u;
}
static __device__ __forceinline__ float b2f(unsigned short h){
  unsigned u = ((unsigned)h) << 16;
  return __builtin_bit_cast(float, u);
}
static __device__ __forceinline__ float rdlane_f(float v, int l){
  return __builtin_bit_cast(float, __builtin_amdgcn_readlane(__builtin_bit_cast(int, v), l));
}

// ---- merged prep: x->bf16 convert | W1/W2 transpose->bf16 | degree histogram ----
__global__ void k_prep(const float* __restrict__ x, unsigned short* __restrict__ xb,
                       const float* __restrict__ W1, const float* __restrict__ W2,
                       unsigned short* __restrict__ W1t, unsigned short* __restrict__ W2t,
                       const int* __restrict__ ei, int* __restrict__ deg){
  const int b = blockIdx.x, t = threadIdx.x;
  if (b < PB_CONV){
    int base = (b * 256 + t) * 8;
    int row = base >> 9;
    u16x8 o;
    if (row < NN){
      const float4* p = (const float4*)(x + base);
      float4 a = p[0], c = p[1];
      o[0]=f2b(a.x); o[1]=f2b(a.y); o[2]=f2b(a.z); o[3]=f2b(a.w);
      o[4]=f2b(c.x); o[5]=f2b(c.y); o[6]=f2b(c.z); o[7]=f2b(c.w);
    } else {
      #pragma unroll
      for (int k=0;k<8;k++) o[k]=0;
    }
    *(u16x8*)(xb + base) = o;
  } else if (b < PB_CONV + PB_TRANS){
    int bb = b - PB_CONV;
    const float* W = (bb < 1024) ? W1 : W2;
    unsigned short* Wt = (bb < 1024) ? W1t : W2t;
    int idx = (bb & 1023) * 256 + t;
    int n = idx >> 9, k = idx & (CH - 1);
    Wt[n * CH + k] = f2b(W[k * CH + n]);
  } else {
    int e4 = ((b - PB_CONV - PB_TRANS) * 256 + t) * 4;
    if (e4 < NE){
      int4 d = *(const int4*)(ei + NE + e4);
      atomicAdd(&deg[d.x], 1); atomicAdd(&deg[d.y], 1);
      atomicAdd(&deg[d.z], 1); atomicAdd(&deg[d.w], 1);
    }
  }
}

// ---- hierarchical scan: block sums -> scan -> scatter ----
__global__ void k_blocksum(const int* __restrict__ deg, int* __restrict__ bsum){
  __shared__ int sh[4];
  const int t = threadIdx.x;
  int i = blockIdx.x * 256 + t;
  int v = (i < NN) ? deg[i] : 0;
  #pragma unroll
  for (int off = 32; off > 0; off >>= 1) v += __shfl_down(v, off, 64);
  if ((t & 63) == 0) sh[t >> 6] = v;
  __syncthreads();
  if (t == 0) bsum[blockIdx.x] = sh[0] + sh[1] + sh[2] + sh[3];
}

__global__ void k_scanoff(const int* __restrict__ bsum, int* __restrict__ boff,
                          int* __restrict__ row_ptr){
  __shared__ int sh[256];
  const int t = threadIdx.x;
  int v = (t < NB) ? bsum[t] : 0;
  sh[t] = v; __syncthreads();
  for (int d = 1; d < 256; d <<= 1){
    int add = (t >= d) ? sh[t - d] : 0;
    __syncthreads();
    sh[t] += add;
    __syncthreads();
  }
  if (t < NB) boff[t] = sh[t] - v;
  if (t == 255) row_ptr[NN] = sh[255];
}

__global__ void k_scatter(const int* __restrict__ deg, const int* __restrict__ boff,
                          int* __restrict__ row_ptr, int* __restrict__ cursor,
                          float* __restrict__ dinv){
  __shared__ int sh[256];
  const int t = threadIdx.x;
  int i = blockIdx.x * 256 + t;
  int d = (i < NN) ? deg[i] : 0;
  sh[t] = d; __syncthreads();
  for (int dd = 1; dd < 256; dd <<= 1){
    int add = (t >= dd) ? sh[t - dd] : 0;
    __syncthreads();
    sh[t] += add;
    __syncthreads();
  }
  if (i < NN){
    int ex = sh[t] - d + boff[blockIdx.x];
    row_ptr[i] = ex; cursor[i] = ex;
    dinv[i] = rsqrtf((float)d + 1.0f);   // +1 self-loop
  }
}

// ---- bucket edges by dst (2 edges/thread) ----
__global__ void k_bucket(const int* __restrict__ ei, int* __restrict__ cursor,
                         int* __restrict__ csr_src){
  int e2 = (blockIdx.x * blockDim.x + threadIdx.x) * 2;
  if (e2 >= NE) return;
  int2 src = *(const int2*)(ei + e2);
  int2 dst = *(const int2*)(ei + NE + e2);
  csr_src[atomicAdd(&cursor[dst.x], 1)] = src.x;
  csr_src[atomicAdd(&cursor[dst.y], 1)] = src.y;
}

// ---- bf16 MFMA GEMM: C[M,512] = A @ Bt^T, 128x256 block tile ----
__launch_bounds__(256, 2)
__global__ void k_gemm(const unsigned short* __restrict__ A,
                       const unsigned short* __restrict__ Bt,
                       unsigned short* __restrict__ C){
  __shared__ __align__(16) unsigned short As[128 * 32];   // 8 KB
  __shared__ __align__(16) unsigned short Bs[256 * 32];   // 16 KB
  const int t = threadIdx.x;
  const int wave = t >> 6, lane = t & 63;
  const int quad = lane >> 4, l15 = lane & 15;
  const int mw = (wave & 1) * 64;        // wave row-block (2 x 64 rows)
  const int nw = (wave >> 1) * 128;      // wave col-block (2 x 128 cols)
  const int rowBase = blockIdx.x * 128;
  const int nBase = blockIdx.y * 256;

  const int lr = lane >> 2;              // row within 16-row chunk
  const int lc = (lane & 3) * 8;         // short offset within 32-short row
  // wave stages A chunks {2w,2w+1} (rows 32w..32w+31), B chunks {4w..4w+3} (rows 64w..64w+63)
  const unsigned short* Ag0 = A  + (size_t)(rowBase + wave * 32 + lr) * CH + lc;
  const unsigned short* Bg0 = Bt + (size_t)(nBase + wave * 64 + lr) * CH + lc;
  unsigned short* Al0 = As + wave * 2 * 512;
  unsigned short* Bl0 = Bs + wave * 4 * 512;

  f32x4 acc[4][8];
  #pragma unroll
  for (int i=0;i<4;i++)
    #pragma unroll
    for (int j=0;j<8;j++) acc[i][j] = 0;

  for (int kb = 0; kb < CH; kb += 32){
    #pragma unroll
    for (int q=0;q<2;q++)
      __builtin_amdgcn_global_load_lds(
        (const __attribute__((address_space(1))) void*)(Ag0 + (size_t)q*16*CH + kb),
        (__attribute__((address_space(3))) void*)(Al0 + q*512), 16, 0, 0);
    #pragma unroll
    for (int q=0;q<4;q++)
      __builtin_amdgcn_global_load_lds(
        (const __attribute__((address_space(1))) void*)(Bg0 + (size_t)q*16*CH + kb),
        (__attribute__((address_space(3))) void*)(Bl0 + q*512), 16, 0, 0);
    __syncthreads();

    bf16x8 af[4], bfr[8];
    #pragma unroll
    for (int i=0;i<4;i++)
      af[i] = __builtin_bit_cast(bf16x8,
              *(const u16x8*)&As[(mw + i*16 + l15) * 32 + quad * 8]);
    #pragma unroll
    for (int j=0;j<8;j++)
      bfr[j] = __builtin_bit_cast(bf16x8,
              *(const u16x8*)&Bs[(nw + j*16 + l15) * 32 + quad * 8]);
    #pragma unroll
    for (int i=0;i<4;i++)
      #pragma unroll
      for (int j=0;j<8;j++)
        acc[i][j] = __builtin_amdgcn_mfma_f32_16x16x32_bf16(af[i], bfr[j], acc[i][j], 0, 0, 0);
    __syncthreads();
  }

  // C/D layout (m89-verified): col = lane&15, row = quad*4 + reg
  #pragma unroll
  for (int i=0;i<4;i++){
    #pragma unroll
    for (int j=0;j<8;j++){
      int r0 = rowBase + mw + i*16 + quad*4;
      int c  = nBase + nw + j*16 + l15;
      #pragma unroll
      for (int r=0;r<4;r++)
        C[(size_t)(r0 + r) * CH + c] = f2b(acc[i][j][r]);
    }
  }
}

// ---- aggregation: relu(dinv_i * sum dinv_j*h_j + dinv_i^2*h_i + b); optional head fuse ----
template<bool HEAD>
__launch_bounds__(256)
__global__ void k_agg(const unsigned short* __restrict__ h, const int* __restrict__ row_ptr,
                      const int* __restrict__ csr_src, const float* __restrict__ dinv,
                      const float* __restrict__ bias, unsigned short* __restrict__ out,
                      const float* __restrict__ Wo, const float* __restrict__ bo,
                      float* __restrict__ logits){
  const int node = blockIdx.x * 4 + (threadIdx.x >> 6);
  const int lane = threadIdx.x & 63;
  float acc[8];
  #pragma unroll
  for (int k=0;k<8;k++) acc[k] = 0.f;
  const int rp = row_ptr[node], re = row_ptr[node + 1];
  for (int base = rp; base < re; base += 64){
    int cnt = re - base; if (cnt > 64) cnt = 64;
    int s = 0; float w = 0.f;
    if (base + lane < re){ s = csr_src[base + lane]; w = dinv[s]; }
    int j = 0;
    for (; j + 8 <= cnt; j += 8){
      int ss[8]; float ww[8]; u16x8 hv[8];
      #pragma unroll
      for (int u=0;u<8;u++){
        ss[u] = __builtin_amdgcn_readlane(s, j + u);
        ww[u] = rdlane_f(w, j + u);
      }
      #pragma unroll
      for (int u=0;u<8;u++)
        hv[u] = *(const u16x8*)(h + (size_t)ss[u] * CH + lane * 8);
      #pragma unroll
      for (int u=0;u<8;u++)
        #pragma unroll
        for (int k=0;k<8;k++) acc[k] += ww[u] * b2f(hv[u][k]);
    }
    for (; j < cnt; j++){
      int ss = __builtin_amdgcn_readlane(s, j);
      float ww = rdlane_f(w, j);
      u16x8 hv = *(const u16x8*)(h + (size_t)ss * CH + lane * 8);
      #pragma unroll
      for (int k=0;k<8;k++) acc[k] += ww * b2f(hv[k]);
    }
  }
  const float di = dinv[node];
  u16x8 hs = *(const u16x8*)(h + (size_t)node * CH + lane * 8);
  const float4* bp = (const float4*)(bias + lane * 8);
  float4 bv0 = bp[0], bv1 = bp[1];
  float bb[8] = {bv0.x,bv0.y,bv0.z,bv0.w,bv1.x,bv1.y,bv1.z,bv1.w};
  if (HEAD){
    const float4* wp = (const float4*)(Wo + lane * 8);
    float4 w0 = wp[0], w1 = wp[1];
    float wv[8] = {w0.x,w0.y,w0.z,w0.w,w1.x,w1.y,w1.z,w1.w};
    float v = 0.f;
    #pragma unroll
    for (int k=0;k<8;k++){
      float r = fmaxf(di * acc[k] + di * di * b2f(hs[k]) + bb[k], 0.f);
      v += r * wv[k];
    }
    #pragma unroll
    for (int off = 32; off > 0; off >>= 1) v += __shfl_down(v, off, 64);
    if (lane == 0) logits[node] = v + bo[0];
  } else {
    u16x8 o;
    #pragma unroll
    for (int k=0;k<8;k++){
      float r = fmaxf(di * acc[k] + di * di * b2f(hs[k]) + bb[k], 0.f);
      o[k] = f2b(r);
    }
    *(u16x8*)(out + (size_t)node * CH + lane * 8) = o;
  }
}

// ---- softmax: 49-block partial (m_b, s_b) + 64-lane online combine ----
__global__ void k_smpart(const float* __restrict__ logits, float* __restrict__ pm,
                         float* __restrict__ ps){
  __shared__ float shm[16], shs[16];
  const int t = threadIdx.x;
  const int i = blockIdx.x * 1024 + t;
  float v = (i < NN) ? logits[i] : -3.4e38f;
  float m = v;
  #pragma unroll
  for (int off = 32; off > 0; off >>= 1) m = fmaxf(m, __shfl_down(m, off, 64));
  if ((t & 63) == 0) shm[t >> 6] = m;
  __syncthreads();
  if (t < 64){
    float mm = (t < 16) ? shm[t] : -3.4e38f;
    #pragma unroll
    for (int off = 8; off > 0; off >>= 1) mm = fmaxf(mm, __shfl_down(mm, off, 64));
    if (t == 0) shm[0] = mm;
  }
  __syncthreads();
  const float bm = shm[0];
  float s = (i < NN) ? expf(v - bm) : 0.f;
  #pragma unroll
  for (int off = 32; off > 0; off >>= 1) s += __shfl_down(s, off, 64);
  if ((t & 63) == 0) shs[t >> 6] = s;
  __syncthreads();
  if (t < 64){
    float sss = (t < 16) ? shs[t] : 0.f;
    #pragma unroll
    for (int off = 8; off > 0; off >>= 1) sss += __shfl_down(sss, off, 64);
    if (t == 0){ pm[blockIdx.x] = bm; ps[blockIdx.x] = sss; }
  }
}

__global__ void k_smfinal(const float* __restrict__ pm, const float* __restrict__ ps,
                          float* __restrict__ scr){
  const int t = threadIdx.x;   // 64 threads
  float m = (t < SMB) ? pm[t] : -3.4e38f;
  float M = m;
  #pragma unroll
  for (int off = 32; off > 0; off >>= 1) M = fmaxf(M, __shfl_down(M, off, 64));
  M = rdlane_f(M, 0);
  float s = (t < SMB) ? ps[t] * expf(m - M) : 0.f;
  #pragma unroll
  for (int off = 32; off > 0; off >>= 1) s += __shfl_down(s, off, 64);
  if (t == 0){ scr[0] = M; scr[1] = s; }
}

__global__ void k_smwrite(const float* __restrict__ logits, const float* __restrict__ scr,
                          float* __restrict__ out){
  int i = blockIdx.x * blockDim.x + threadIdx.x;
  if (i >= NN) return;
  out[i] = expf(logits[i] - scr[0]) / scr[1];
}

extern "C" void kernel_launch(void* const* d_in, const int* in_sizes, int n_in,
                              void* d_out, int out_size, void* d_ws, size_t ws_size,
                              hipStream_t stream){
  const float* x  = (const float*)d_in[0];
  const int*   ei = (const int*)d_in[1];
  const float* W1 = (const float*)d_in[2];
  const float* b1 = (const float*)d_in[3];
  const float* W2 = (const float*)d_in[4];
  const float* b2 = (const float*)d_in[5];
  const float* Wo = (const float*)d_in[6];
  const float* bo = (const float*)d_in[7];
  float* out = (float*)d_out;

  char* ws = (char*)d_ws;
  size_t off = 0;
  auto alloc = [&](size_t bytes) -> void* {
    void* p = ws + off;
    off = (off + bytes + 255) & ~(size_t)255;
    return p;
  };
  unsigned short* B0  = (unsigned short*)alloc((size_t)NP * CH * 2);
  unsigned short* B1  = (unsigned short*)alloc((size_t)NP * CH * 2);
  unsigned short* W1t = (unsigned short*)alloc((size_t)CH * CH * 2);
  unsigned short* W2t = (unsigned short*)alloc((size_t)CH * CH * 2);
  int*   deg     = (int*)alloc((size_t)NN * 4);
  float* dinv    = (float*)alloc((size_t)NN * 4);
  int*   row_ptr = (int*)alloc((size_t)(NN + 1) * 4);
  int*   cursor  = (int*)alloc((size_t)NN * 4);
  int*   csr     = (int*)alloc((size_t)NE * 4);
  float* logits  = (float*)alloc((size_t)NN * 4);
  int*   bsum    = (int*)alloc((size_t)NB * 4);
  int*   boff    = (int*)alloc((size_t)NB * 4);
  float* pm      = (float*)alloc((size_t)SMB * 4);
  float* ps      = (float*)alloc((size_t)SMB * 4);
  float* scr     = (float*)alloc(256);

  hipMemsetAsync(deg, 0, (size_t)NN * 4, stream);
  k_prep<<<PB_CONV + PB_TRANS + PB_DEG, 256, 0, stream>>>(x, B0, W1, W2, W1t, W2t, ei, deg);
  k_blocksum<<<NB, 256, 0, stream>>>(deg, bsum);
  k_scanoff<<<1, 256, 0, stream>>>(bsum, boff, row_ptr);
  k_scatter<<<NB, 256, 0, stream>>>(deg, boff, row_ptr, cursor, dinv);
  k_bucket<<<(NE / 2 + 255) / 256, 256, 0, stream>>>(ei, cursor, csr);

  k_gemm<<<dim3(NP / 128, CH / 256), 256, 0, stream>>>(B0, W1t, B1);
  k_agg<false><<<NN / 4, 256, 0, stream>>>(B1, row_ptr, csr, dinv, b1, B0,
                                           Wo, bo, logits);
  k_gemm<<<dim3(NP / 128, CH / 256), 256, 0, stream>>>(B0, W2t, B1);
  k_agg<true><<<NN / 4, 256, 0, stream>>>(B1, row_ptr, csr, dinv, b2, B0,
                                          Wo, bo, logits);

  k_smpart<<<SMB, 1024, 0, stream>>>(logits, pm, ps);
  k_smfinal<<<1, 64, 0, stream>>>(pm, ps, scr);
  k_smwrite<<<(NN + 255) / 256, 256, 0, stream>>>(logits, scr, out);
}